// Round 5
// baseline (4228.120 us; speedup 1.0000x reference)
//
#include <hip/hip_runtime.h>
#include <cmath>

#define B 64
#define S 4096
#define NI 16
#define H 128
#define F 144   // H + NI
#define CH 16   // timesteps per chunk
#define NCH (S / CH)
#define GIP 132 // padded gi row (12*132 % 32 = 16 -> worst 2-way on writes, free)

typedef _Float16 h2   __attribute__((ext_vector_type(2)));
typedef _Float16 h4v  __attribute__((ext_vector_type(4)));
typedef _Float16 h8   __attribute__((ext_vector_type(8)));
typedef float    f4v  __attribute__((ext_vector_type(4)));
typedef unsigned long long u64;
typedef u64 u64x2 __attribute__((ext_vector_type(2)));

__device__ __forceinline__ float rcp_fast(float x) { return __builtin_amdgcn_rcpf(x); }
__device__ __forceinline__ float sigf(float x) {
    return rcp_fast(1.0f + __expf(-x));
}
// tanh(x) = 2*sigmoid(2x) - 1
__device__ __forceinline__ float tanh_fast(float x) {
    const float e = __expf(-2.0f * x);
    return fmaf(2.0f, rcp_fast(1.0f + e), -1.0f);
}
// both lanes of each pair end with the 2-lane sum
__device__ __forceinline__ float pair_reduce(float v) {
    int t1 = __builtin_amdgcn_mov_dpp(__float_as_int(v), 0xB1, 0xf, 0xf, true); // xor 1
    v += __int_as_float(t1);
    return v;
}
__device__ __forceinline__ h2 cvt2(float a, float b) {
    h2 r; r[0] = (_Float16)a; r[1] = (_Float16)b; return r;
}
// convert 8 consecutive fp32 -> 4 packed half2 regs
__device__ __forceinline__ void cvt8(const float* p, h2* w) {
    const float4 f0 = ((const float4*)p)[0];
    const float4 f1 = ((const float4*)p)[1];
    w[0] = cvt2(f0.x, f0.y); w[1] = cvt2(f0.z, f0.w);
    w[2] = cvt2(f1.x, f1.y); w[3] = cvt2(f1.z, f1.w);
}
// convert 8 consecutive fp32 -> h8
__device__ __forceinline__ h8 cvt8v(const float* p) {
    const float4 f0 = ((const float4*)p)[0];
    const float4 f1 = ((const float4*)p)[1];
    h8 r;
    r[0] = (_Float16)f0.x; r[1] = (_Float16)f0.y;
    r[2] = (_Float16)f0.z; r[3] = (_Float16)f0.w;
    r[4] = (_Float16)f1.x; r[5] = (_Float16)f1.y;
    r[6] = (_Float16)f1.z; r[7] = (_Float16)f1.w;
    return r;
}
__device__ __forceinline__ void pin_h2(h2& v) {
    int t = __builtin_bit_cast(int, v);
    asm volatile("" : "+v"(t));
    v = __builtin_bit_cast(h2, t);
}
__device__ __forceinline__ void pin_f(float& v) {
    asm volatile("" : "+v"(v));
}
__device__ __forceinline__ void pin_h8(h8& v) {
    u64x2 t = __builtin_bit_cast(u64x2, v);
    u64 a = t[0], b = t[1];
    asm volatile("" : "+v"(a), "+v"(b));
    t[0] = a; t[1] = b;
    v = __builtin_bit_cast(h8, t);
}
__device__ __forceinline__ f4v mfma16(h8 a, h8 b, f4v c) {
    return __builtin_amdgcn_mfma_f32_16x16x32_f16(a, b, c, 0, 0, 0);
}

// ---------------------------------------------------------------------------
// Fully fused 2-layer GRU: one block per batch, both layers + in-LDS handoff.
// 64 blocks x 768 threads (12 waves):
//   waves 0-3 : L0 recurrence (pair K-split; x-dots inline, x staged in LDS)
//   waves 4-7 : L1 recurrence (pair K-split; input projection gi from LDS)
//   waves 8-11: helpers — once per chunk MFMA gi1 = y0 . W_ih1^T + bias from
//               the LDS y0 buffer, and flush finished h1 chunks to global.
// Pipeline lag: during chunk c, L0 computes chunk c, the helper projects
// chunk c-1, L1 processes chunk c-2. Loop runs S + 2*CH steps.
// No inter-block communication: no flags, no atomics, no y0 global traffic.
// ---------------------------------------------------------------------------
__global__ __launch_bounds__(768, 1)
void gru_fused(const float* __restrict__ x,
               const float* __restrict__ w_ih0, const float* __restrict__ w_hh0,
               const float* __restrict__ b_ih0, const float* __restrict__ b_hh0,
               const float* __restrict__ w_ih1, const float* __restrict__ w_hh1,
               const float* __restrict__ b_ih1, const float* __restrict__ b_hh1,
               _Float16* __restrict__ h_out)
{
    __shared__ __align__(16) _Float16 sH0[2][H];           // 512 B
    __shared__ __align__(16) _Float16 sH1[2][H];           // 512 B
    __shared__ __align__(16) _Float16 sX[2][CH][NI];       // 1 KB
    __shared__ __align__(16) _Float16 sY[2][CH][H];        // 8 KB  (y0 handoff)
    __shared__ __align__(16) _Float16 sHo[2][CH][H];       // 8 KB  (h1 staging)
    __shared__ __align__(16) float    sGi[2][CH][3][GIP];  // 50.7 KB

    const int tid  = threadIdx.x;
    const int b    = blockIdx.x;
    const int wave = tid >> 6;
    const int lane = tid & 63;
    const int role = wave >> 2;        // 0: L0 rec, 1: L1 rec, 2: helper
    const int rt   = tid & 255;
    const int jr   = rt >> 1;          // rec: output unit 0..127
    const int mr   = rt & 1;           // rec: K half
    const int wv   = wave & 3;         // helper wave 0..3
    const int nl   = lane & 15;        // helper: A row / B col n
    const int q    = lane >> 4;        // helper: k-group / C row group

    const float* xb = x + (size_t)b * S * NI;
    _Float16*    hb = h_out + (size_t)b * S * H;

    h2 wc[96];           // rec: W_hh, [0..31] r, [32..63] z, [64..95] hn
    h2 wx[12];           // L0 rec: W_ih0 slice, [0..3] r, [4..7] z, [8..11] in
    float b_r = 0.f, b_z = 0.f, b_in = 0.f, b_hn = 0.f;
    h8 Bf[6][4];         // helper: stationary W_ih1 fragments
    float bias[6];

    if (role < 2) {
        const float* whh = role == 0 ? w_hh0 : w_hh1;
#pragma unroll
        for (int g = 0; g < 3; g++)
#pragma unroll
            for (int i = 0; i < 8; i++) {
                const int ii = (i + 4 * mr) & 7;     // addr stagger
                cvt8(whh + (size_t)(g * H + jr) * H + 64 * mr + 8 * ii,
                     &wc[g * 32 + 4 * i]);
            }
#pragma unroll
        for (int i = 0; i < 96; i++) pin_h2(wc[i]);
        if (role == 0) {
#pragma unroll
            for (int g = 0; g < 3; g++)
                cvt8(w_ih0 + (size_t)(g * H + jr) * NI + 8 * mr, &wx[g * 4]);
#pragma unroll
            for (int i = 0; i < 12; i++) pin_h2(wx[i]);
            b_r  = b_ih0[jr]       + b_hh0[jr];
            b_z  = b_ih0[H + jr]   + b_hh0[H + jr];
            b_in = b_ih0[2*H + jr];
            b_hn = b_hh0[2*H + jr];
            pin_f(b_r); pin_f(b_z); pin_f(b_in);
            if (rt < H) sH0[0][rt] = (_Float16)0.0f;
        } else {
            b_hn = b_hh1[2*H + jr];
            if (rt < H) sH1[0][rt] = (_Float16)0.0f;
        }
        pin_f(b_hn);
    } else {
#pragma unroll
        for (int tt = 0; tt < 6; tt++) {
            const int n = 16 * (wv * 6 + tt) + nl;
            const float* wr = w_ih1 + (size_t)n * H;
#pragma unroll
            for (int kc = 0; kc < 4; kc++) {
                Bf[tt][kc] = cvt8v(wr + 32 * kc + 8 * q);
                pin_h8(Bf[tt][kc]);
            }
            bias[tt] = b_ih1[n] + (n < 2 * H ? b_hh1[n] : 0.0f);
            pin_f(bias[tt]);
        }
    }

    // x chunk 0 staging + chunk-1 prefetch (L0 rec lanes 0..63)
    float4 xreg = {0.f, 0.f, 0.f, 0.f};
    if (tid < 64) {
        const float4 v = ((const float4*)xb)[tid];
        h4v p; p[0] = (_Float16)v.x; p[1] = (_Float16)v.y;
               p[2] = (_Float16)v.z; p[3] = (_Float16)v.w;
        ((h4v*)&sX[0][0][0])[tid] = p;
        xreg = ((const float4*)(xb + CH * NI))[tid];
    }
    float hprev = 0.0f;
    __syncthreads();

    for (int t = 0; t < S + 2 * CH; t++) {
        const int cur = t & 1;
        const int c   = t >> 4;
        const int tw  = t & (CH - 1);

        if (role == 0) {
            if (t < S) {
                // stage next x chunk (prefetched a chunk ahead)
                if (tw == 0 && tid < 64) {
                    const int cn = c + 1;
                    if (cn < NCH) {
                        h4v p; p[0] = (_Float16)xreg.x; p[1] = (_Float16)xreg.y;
                               p[2] = (_Float16)xreg.z; p[3] = (_Float16)xreg.w;
                        ((h4v*)&sX[cn & 1][0][0])[tid] = p;
                        if (cn + 1 < NCH)
                            xreg = ((const float4*)(xb + (size_t)(cn + 1) * CH * NI))[tid];
                    }
                }
                const float4* hv = (const float4*)&sH0[cur][0];
                float ar = 0.f, az = 0.f, ahn = 0.f;
#pragma unroll
                for (int i = 0; i < 8; i++) {
                    const int ii = (i + 4 * mr) & 7;     // addr stagger
                    const float4 qv = hv[8 * mr + ii];
                    const h2 p0 = __builtin_bit_cast(h2, qv.x);
                    const h2 p1 = __builtin_bit_cast(h2, qv.y);
                    const h2 p2 = __builtin_bit_cast(h2, qv.z);
                    const h2 p3 = __builtin_bit_cast(h2, qv.w);
                    ar  = __builtin_amdgcn_fdot2(p0, wc[4*i+0],    ar,  false);
                    ar  = __builtin_amdgcn_fdot2(p1, wc[4*i+1],    ar,  false);
                    ar  = __builtin_amdgcn_fdot2(p2, wc[4*i+2],    ar,  false);
                    ar  = __builtin_amdgcn_fdot2(p3, wc[4*i+3],    ar,  false);
                    az  = __builtin_amdgcn_fdot2(p0, wc[32+4*i+0], az,  false);
                    az  = __builtin_amdgcn_fdot2(p1, wc[32+4*i+1], az,  false);
                    az  = __builtin_amdgcn_fdot2(p2, wc[32+4*i+2], az,  false);
                    az  = __builtin_amdgcn_fdot2(p3, wc[32+4*i+3], az,  false);
                    ahn = __builtin_amdgcn_fdot2(p0, wc[64+4*i+0], ahn, false);
                    ahn = __builtin_amdgcn_fdot2(p1, wc[64+4*i+1], ahn, false);
                    ahn = __builtin_amdgcn_fdot2(p2, wc[64+4*i+2], ahn, false);
                    ahn = __builtin_amdgcn_fdot2(p3, wc[64+4*i+3], ahn, false);
                }
                const float4 xq = *(const float4*)&sX[c & 1][tw][8 * mr];
                const h2 x0 = __builtin_bit_cast(h2, xq.x);
                const h2 x1 = __builtin_bit_cast(h2, xq.y);
                const h2 x2 = __builtin_bit_cast(h2, xq.z);
                const h2 x3 = __builtin_bit_cast(h2, xq.w);
                float ain = 0.f;
                ar  = __builtin_amdgcn_fdot2(x0, wx[0],  ar,  false);
                ar  = __builtin_amdgcn_fdot2(x1, wx[1],  ar,  false);
                ar  = __builtin_amdgcn_fdot2(x2, wx[2],  ar,  false);
                ar  = __builtin_amdgcn_fdot2(x3, wx[3],  ar,  false);
                az  = __builtin_amdgcn_fdot2(x0, wx[4],  az,  false);
                az  = __builtin_amdgcn_fdot2(x1, wx[5],  az,  false);
                az  = __builtin_amdgcn_fdot2(x2, wx[6],  az,  false);
                az  = __builtin_amdgcn_fdot2(x3, wx[7],  az,  false);
                ain = __builtin_amdgcn_fdot2(x0, wx[8],  ain, false);
                ain = __builtin_amdgcn_fdot2(x1, wx[9],  ain, false);
                ain = __builtin_amdgcn_fdot2(x2, wx[10], ain, false);
                ain = __builtin_amdgcn_fdot2(x3, wx[11], ain, false);

                const float r  = sigf(pair_reduce(ar) + b_r);
                const float z  = sigf(pair_reduce(az) + b_z);
                const float n  = tanh_fast(pair_reduce(ain) + b_in
                                           + r * (pair_reduce(ahn) + b_hn));
                const float hn = n + z * (hprev - n);
                hprev = hn;
                if (mr == 0) {
                    sH0[cur ^ 1][jr]  = (_Float16)hn;
                    sY[c & 1][tw][jr] = (_Float16)hn;
                }
            }
        } else if (role == 1) {
            if (t >= 2 * CH) {   // processing h1 chunk c-2 (gi in buffer c&1)
                const float gr = sGi[c & 1][tw][0][jr];
                const float gz = sGi[c & 1][tw][1][jr];
                const float gn = sGi[c & 1][tw][2][jr];
                const float4* hv = (const float4*)&sH1[cur][0];
                float ar = 0.f, az = 0.f, ahn = 0.f;
#pragma unroll
                for (int i = 0; i < 8; i++) {
                    const int ii = (i + 4 * mr) & 7;     // addr stagger
                    const float4 qv = hv[8 * mr + ii];
                    const h2 p0 = __builtin_bit_cast(h2, qv.x);
                    const h2 p1 = __builtin_bit_cast(h2, qv.y);
                    const h2 p2 = __builtin_bit_cast(h2, qv.z);
                    const h2 p3 = __builtin_bit_cast(h2, qv.w);
                    ar  = __builtin_amdgcn_fdot2(p0, wc[4*i+0],    ar,  false);
                    ar  = __builtin_amdgcn_fdot2(p1, wc[4*i+1],    ar,  false);
                    ar  = __builtin_amdgcn_fdot2(p2, wc[4*i+2],    ar,  false);
                    ar  = __builtin_amdgcn_fdot2(p3, wc[4*i+3],    ar,  false);
                    az  = __builtin_amdgcn_fdot2(p0, wc[32+4*i+0], az,  false);
                    az  = __builtin_amdgcn_fdot2(p1, wc[32+4*i+1], az,  false);
                    az  = __builtin_amdgcn_fdot2(p2, wc[32+4*i+2], az,  false);
                    az  = __builtin_amdgcn_fdot2(p3, wc[32+4*i+3], az,  false);
                    ahn = __builtin_amdgcn_fdot2(p0, wc[64+4*i+0], ahn, false);
                    ahn = __builtin_amdgcn_fdot2(p1, wc[64+4*i+1], ahn, false);
                    ahn = __builtin_amdgcn_fdot2(p2, wc[64+4*i+2], ahn, false);
                    ahn = __builtin_amdgcn_fdot2(p3, wc[64+4*i+3], ahn, false);
                }
                const float r  = sigf(pair_reduce(ar) + gr);
                const float z  = sigf(pair_reduce(az) + gz);
                const float n  = tanh_fast(gn + r * (pair_reduce(ahn) + b_hn));
                const float hn = n + z * (hprev - n);
                hprev = hn;
                if (mr == 0) {
                    sH1[cur ^ 1][jr]   = (_Float16)hn;
                    sHo[c & 1][tw][jr] = (_Float16)hn;   // h1 chunk c-2, parity c&1
                }
            }
        } else {
            if (tw == 0) {
                // flush h1 chunk k = c-3 (completed during chunk c-1)
                if (c >= 3) {
                    const int k   = c - 3;
                    const int idx = tid - 512;
                    const uint2 v0 = ((const uint2*)&sHo[k & 1][0][0])[idx];
                    const uint2 v1 = ((const uint2*)&sHo[k & 1][0][0])[idx + 256];
                    ((uint2*)(hb + (size_t)k * CH * H))[idx]       = v0;
                    ((uint2*)(hb + (size_t)k * CH * H))[idx + 256] = v1;
                }
            } else if (tw == 1) {
                // project gi1 for y0 chunk k = c-1 (in sY since end of chunk c-1)
                if (c >= 1 && c <= NCH) {
                    const int k = c - 1;
                    const _Float16* yr = &sY[k & 1][nl][0];
                    h8 A[4];
#pragma unroll
                    for (int kc = 0; kc < 4; kc++)
                        A[kc] = *(const h8*)(yr + 32 * kc + 8 * q);
                    f4v accs[6];
#pragma unroll
                    for (int tt = 0; tt < 6; tt++) { f4v zz = {0.f,0.f,0.f,0.f}; accs[tt] = zz; }
#pragma unroll
                    for (int kc = 0; kc < 4; kc++)
#pragma unroll
                        for (int tt = 0; tt < 6; tt++)
                            accs[tt] = mfma16(A[kc], Bf[tt][kc], accs[tt]);
                    float* gp = &sGi[k & 1][0][0][0];
#pragma unroll
                    for (int tt = 0; tt < 6; tt++) {
                        const int n = 16 * (wv * 6 + tt) + nl;
                        const int g = n >> 7, jj = n & 127;
#pragma unroll
                        for (int r = 0; r < 4; r++)
                            gp[((4 * q + r) * 3 + g) * GIP + jj] = accs[tt][r] + bias[tt];
                    }
                }
            }
        }
        __syncthreads();
    }
    // final h1 chunk (NCH-1, completed during the last loop chunk)
    if (role == 2) {
        const int k   = NCH - 1;
        const int idx = tid - 512;
        const uint2 v0 = ((const uint2*)&sHo[k & 1][0][0])[idx];
        const uint2 v1 = ((const uint2*)&sHo[k & 1][0][0])[idx + 256];
        ((uint2*)(hb + (size_t)k * CH * H))[idx]       = v0;
        ((uint2*)(hb + (size_t)k * CH * H))[idx + 256] = v1;
    }
}

// ---------------------------------------------------------------------------
// MFMA MLP head. 512 blocks x 256 threads (4 independent waves, no barriers).
// ---------------------------------------------------------------------------
__global__ __launch_bounds__(256, 2)
void head_mfma(const _Float16* __restrict__ h1, const float* __restrict__ x,
               const float* __restrict__ w1, const float* __restrict__ b1,
               const float* __restrict__ w2, const float* __restrict__ b2,
               float* __restrict__ inc)
{
    const int wave = threadIdx.x >> 6;
    const int lane = threadIdx.x & 63;
    const int nl   = lane & 15;
    const int q    = lane >> 4;

    h8 Bf[4][5];
    float b1v[4], w2v[4];
#pragma unroll
    for (int t = 0; t < 4; t++) {
        const int n = 16 * t + nl;
        const float* wr = w1 + (size_t)n * F;
#pragma unroll
        for (int c = 0; c < 4; c++)
            Bf[t][c] = cvt8v(wr + 32 * c + 8 * q);
        if (q < 2) Bf[t][4] = cvt8v(wr + 128 + 8 * q);
        else { h8 z = {};
               Bf[t][4] = z; }
        b1v[t] = b1[n];
        w2v[t] = w2[n];
    }
    const float b2v = b2[0];

    const int gw = blockIdx.x * 4 + wave;

    for (int it = 0; it < 8; it++) {
        const int row0 = (gw * 8 + it) * 16;
        const int rm   = row0 + nl;

        const _Float16* hp = h1 + (size_t)rm * H;
        h8 A0 = *(const h8*)(hp + 8 * q);
        h8 A1 = *(const h8*)(hp + 32 + 8 * q);
        h8 A2 = *(const h8*)(hp + 64 + 8 * q);
        h8 A3 = *(const h8*)(hp + 96 + 8 * q);
        h8 A4;
        if (q < 2) A4 = cvt8v(x + (size_t)rm * NI + 8 * q);
        else { h8 z = {}; A4 = z; }

        f4v acc0 = {0.f,0.f,0.f,0.f}, acc1 = {0.f,0.f,0.f,0.f};
        f4v acc2 = {0.f,0.f,0.f,0.f}, acc3 = {0.f,0.f,0.f,0.f};
        acc0 = mfma16(A0, Bf[0][0], acc0); acc1 = mfma16(A0, Bf[1][0], acc1);
        acc2 = mfma16(A0, Bf[2][0], acc2); acc3 = mfma16(A0, Bf[3][0], acc3);
        acc0 = mfma16(A1, Bf[0][1], acc0); acc1 = mfma16(A1, Bf[1][1], acc1);
        acc2 = mfma16(A1, Bf[2][1], acc2); acc3 = mfma16(A1, Bf[3][1], acc3);
        acc0 = mfma16(A2, Bf[0][2], acc0); acc1 = mfma16(A2, Bf[1][2], acc1);
        acc2 = mfma16(A2, Bf[2][2], acc2); acc3 = mfma16(A2, Bf[3][2], acc3);
        acc0 = mfma16(A3, Bf[0][3], acc0); acc1 = mfma16(A3, Bf[1][3], acc1);
        acc2 = mfma16(A3, Bf[2][3], acc2); acc3 = mfma16(A3, Bf[3][3], acc3);
        acc0 = mfma16(A4, Bf[0][4], acc0); acc1 = mfma16(A4, Bf[1][4], acc1);
        acc2 = mfma16(A4, Bf[2][4], acc2); acc3 = mfma16(A4, Bf[3][4], acc3);

        float rs[4];
#pragma unroll
        for (int r = 0; r < 4; r++) {
            rs[r] = fmaxf(acc0[r] + b1v[0], 0.f) * w2v[0]
                  + fmaxf(acc1[r] + b1v[1], 0.f) * w2v[1]
                  + fmaxf(acc2[r] + b1v[2], 0.f) * w2v[2]
                  + fmaxf(acc3[r] + b1v[3], 0.f) * w2v[3];
        }
#pragma unroll
        for (int off = 1; off < 16; off <<= 1) {
#pragma unroll
            for (int r = 0; r < 4; r++)
                rs[r] += __shfl_xor(rs[r], off, 64);
        }
        if (nl == 0) {
            float4 o;
            o.x = tanh_fast(rs[0] + b2v) * 0.125f;
            o.y = tanh_fast(rs[1] + b2v) * 0.125f;
            o.z = tanh_fast(rs[2] + b2v) * 0.125f;
            o.w = tanh_fast(rs[3] + b2v) * 0.125f;
            *(float4*)(inc + row0 + 4 * q) = o;
        }
    }
}

// ---------------------------------------------------------------------------
// Inclusive cumsum over S per batch + initial offset. One block per batch.
// ---------------------------------------------------------------------------
__global__ __launch_bounds__(256)
void cumsum_kernel(const float* __restrict__ inc, const float* __restrict__ init,
                   float* __restrict__ out)
{
    __shared__ float sW[4];
    const int b = blockIdx.x;
    const int tid = threadIdx.x;
    const int lane = tid & 63;
    const int wid = tid >> 6;

    const float* ib = inc + (size_t)b * S;
    float v[16];
#pragma unroll
    for (int i = 0; i < 16; i++) v[i] = ib[tid * 16 + i];

    float run = 0.f;
#pragma unroll
    for (int i = 0; i < 16; i++) { run += v[i]; v[i] = run; }

    float t = run;
#pragma unroll
    for (int off = 1; off < 64; off <<= 1) {
        float u = __shfl_up(t, off, 64);
        if (lane >= off) t += u;
    }
    const float excl = t - run;
    if (lane == 63) sW[wid] = t;
    __syncthreads();

    float wo = 0.f;
#pragma unroll
    for (int w = 0; w < 4; w++) if (w < wid) wo += sW[w];

    const float prefix = wo + excl + init[0];
    float* ob = out + (size_t)b * S;
#pragma unroll
    for (int i = 0; i < 16; i++) ob[tid * 16 + i] = prefix + v[i];
}

// ---------------------------------------------------------------------------
extern "C" void kernel_launch(void* const* d_in, const int* in_sizes, int n_in,
                              void* d_out, int out_size, void* d_ws, size_t ws_size,
                              hipStream_t stream)
{
    (void)in_sizes; (void)n_in; (void)out_size; (void)ws_size;
    const float* x     = (const float*)d_in[0];
    const float* w_ih0 = (const float*)d_in[1];
    const float* w_hh0 = (const float*)d_in[2];
    const float* b_ih0 = (const float*)d_in[3];
    const float* b_hh0 = (const float*)d_in[4];
    const float* w_ih1 = (const float*)d_in[5];
    const float* w_hh1 = (const float*)d_in[6];
    const float* b_ih1 = (const float*)d_in[7];
    const float* b_hh1 = (const float*)d_in[8];
    const float* w1    = (const float*)d_in[9];
    const float* b1    = (const float*)d_in[10];
    const float* w2    = (const float*)d_in[11];
    const float* b2    = (const float*)d_in[12];
    const float* init  = (const float*)d_in[13];
    float* out = (float*)d_out;

    _Float16* hbuf = (_Float16*)d_ws;                               // 64 MB fp16
    float* incbuf  = (float*)((char*)d_ws + (size_t)B * S * H * 2); // 1 MB

    hipLaunchKernelGGL(gru_fused, dim3(B), dim3(768), 0, stream,
                       x, w_ih0, w_hh0, b_ih0, b_hh0,
                       w_ih1, w_hh1, b_ih1, b_hh1, hbuf);
    hipLaunchKernelGGL(head_mfma, dim3(512), dim3(256), 0, stream,
                       hbuf, x, w1, b1, w2, b2, incbuf);
    hipLaunchKernelGGL(cumsum_kernel, dim3(B), dim3(256), 0, stream,
                       incbuf, init, out);
}